// Round 10
// baseline (34884.726 us; speedup 1.0000x reference)
//
#include <hip/hip_runtime.h>
#include <hip/hip_bf16.h>
#include <cstdint>
#include <cstddef>

#define T_LEN 16384
#define ETS 4
#define C1T 1796
#define CHUNK 128
#define CHUNK_LOG 7
#define NCHUNK (T_LEN / CHUNK)
#define NW 4

typedef _Float16 half8 __attribute__((ext_vector_type(8)));
typedef float f32x4 __attribute__((ext_vector_type(4)));
typedef int int4v __attribute__((ext_vector_type(4)));

// ---------------- prep: transposes + bias sums + f16 MFMA weight fragments ----------------
// Row permutation: p = 4*u + g  ->  orig row = g*256 + u
__global__ void prep_kernel(const float* __restrict__ obs_w,
                            const float* __restrict__ wih0,
                            const float* __restrict__ wih1,
                            const float* __restrict__ whh0,
                            const float* __restrict__ whh1,
                            const float* __restrict__ bih0, const float* __restrict__ bhh0,
                            const float* __restrict__ bih1, const float* __restrict__ bhh1,
                            float* __restrict__ obs_wT,    // [1600][128]
                            float* __restrict__ wih0T,     // [192][1024] permuted cols, zero-pad k>=177
                            float* __restrict__ wih1T,     // [256][1024] permuted cols
                            _Float16* __restrict__ wfrag,  // [2][64rb][8kb][64lane][8]
                            float* __restrict__ bias0, float* __restrict__ bias1) {
  int i = blockIdx.x * blockDim.x + threadIdx.x;   // 2048*256 = 524288 threads
  {
    int layer = i >> 18;
    int r = i & 262143;
    int rb = r >> 12;
    int kb = (r >> 9) & 7;
    int lane = (r >> 3) & 63;
    int j = r & 7;
    int row_p = rb * 16 + (lane & 15);
    int k = kb * 32 + (lane >> 4) * 8 + j;
    int orig = (row_p & 3) * 256 + (row_p >> 2);
    const float* src = layer ? whh1 : whh0;
    wfrag[i] = (_Float16)src[orig * 256 + k];
  }
  if (i < 1600 * 128) { int k = i >> 7, o = i & 127; obs_wT[i] = obs_w[o * 1600 + k]; }
  if (i < 192 * 1024) {
    int k = i >> 10, p = i & 1023;
    int orig = (p & 3) * 256 + (p >> 2);
    wih0T[i] = (k < 177) ? wih0[orig * 177 + k] : 0.f;
  }
  if (i < 256 * 1024) {
    int k = i >> 10, p = i & 1023;
    int orig = (p & 3) * 256 + (p >> 2);
    wih1T[i] = wih1[orig * 256 + k];
  }
  if (i < 1024) {
    int orig = (i & 3) * 256 + (i >> 2);
    bias0[i] = bih0[orig] + bhh0[orig];
    bias1[i] = bih1[orig] + bhh1[orig];
  }
}

// ---------------- encoder (unchanged, verified) ----------------
__global__ __launch_bounds__(256) void encoder_kernel(
    const float* __restrict__ fov, const float* __restrict__ own_pos,
    const float* __restrict__ opponent, const float* __restrict__ cost,
    const int* __restrict__ action,
    const float* __restrict__ w1, const float* __restrict__ b1,
    const float* __restrict__ w2, const float* __restrict__ b2,
    const float* __restrict__ obs_wT, const float* __restrict__ obs_b,
    const float* __restrict__ pos_w, const float* __restrict__ pos_b,
    const float* __restrict__ opp_w, const float* __restrict__ opp_b,
    const float* __restrict__ act_emb,
    float* __restrict__ feat) {
  __shared__ float w1s[864];
  __shared__ float b1s[32];
  __shared__ float inp[ETS * 3 * 7 * 7];
  __shared__ __align__(16) float c1[ETS * C1T];
  __shared__ __align__(16) float c2s[1600 * ETS];
  __shared__ float red[4 * 128];
  int tid = threadIdx.x;
  int t0 = blockIdx.x * ETS;

  for (int i = tid; i < 864; i += 256) w1s[i] = w1[i];
  if (tid < 32) b1s[tid] = b1[tid];
  for (int i = tid; i < ETS * 3 * 49; i += 256) inp[i] = 0.f;
  for (int i = tid; i < ETS * C1T; i += 256) c1[i] = 0.f;
  __syncthreads();
  for (int i = tid; i < ETS * 75; i += 256) {
    int t = i / 75, r = i % 75;
    int y = r / 15, x = (r / 3) % 5, ch = r % 3;
    inp[((t * 3 + ch) * 7 + (y + 1)) * 7 + (x + 1)] = fov[(size_t)(t0 + t) * 75 + r];
  }
  __syncthreads();
  for (int i = tid; i < ETS * 800; i += 256) {
    int t = i / 800, r = i % 800;
    int oc = r / 25, p = r % 25, y = p / 5, x = p % 5;
    float s = b1s[oc];
#pragma unroll
    for (int ch = 0; ch < 3; ++ch)
#pragma unroll
      for (int ky = 0; ky < 3; ++ky)
#pragma unroll
        for (int kx = 0; kx < 3; ++kx)
          s += inp[((t * 3 + ch) * 7 + y + ky) * 7 + x + kx] * w1s[oc * 27 + ch * 9 + ky * 3 + kx];
    c1[t * C1T + (oc * 7 + y + 1) * 8 + (x + 1)] = fmaxf(s, 0.f);
  }
  __syncthreads();
  {
    int oc = tid >> 2, tt = tid & 3;
    float acc[25];
    float bv = b2[oc];
#pragma unroll
    for (int p = 0; p < 25; ++p) acc[p] = bv;
    for (int ic = 0; ic < 32; ++ic) {
      float pl[56];
      const float* base = &c1[tt * C1T + ic * 56];
#pragma unroll
      for (int qq = 0; qq < 14; ++qq) {
        float4 v = *(const float4*)(base + qq * 4);
        pl[qq * 4 + 0] = v.x; pl[qq * 4 + 1] = v.y; pl[qq * 4 + 2] = v.z; pl[qq * 4 + 3] = v.w;
      }
      const float* wrow = &w2[(size_t)(oc * 32 + ic) * 9];
#pragma unroll
      for (int ky = 0; ky < 3; ++ky)
#pragma unroll
        for (int kx = 0; kx < 3; ++kx) {
          float wv = wrow[ky * 3 + kx];
#pragma unroll
          for (int p = 0; p < 25; ++p) {
            int y = p / 5, x = p % 5;
            acc[p] += pl[(y + ky) * 8 + (x + kx)] * wv;
          }
        }
    }
#pragma unroll
    for (int p = 0; p < 25; ++p)
      c2s[(oc * 25 + p) * ETS + tt] = fmaxf(acc[p], 0.f);
  }
  __syncthreads();
  {
    int o = tid & 127, kh = tid >> 7;
    float a0 = 0, a1 = 0, a2 = 0, a3 = 0;
    for (int k = kh * 800; k < kh * 800 + 800; ++k) {
      float wv = obs_wT[k * 128 + o];
      float4 cv = *(const float4*)&c2s[k * ETS];
      a0 += cv.x * wv; a1 += cv.y * wv; a2 += cv.z * wv; a3 += cv.w * wv;
    }
    if (kh == 1) { red[0 * 128 + o] = a0; red[1 * 128 + o] = a1; red[2 * 128 + o] = a2; red[3 * 128 + o] = a3; }
    __syncthreads();
    if (kh == 0) {
      float ob = obs_b[o];
      feat[(size_t)(t0 + 0) * 192 + o] = a0 + red[0 * 128 + o] + ob;
      feat[(size_t)(t0 + 1) * 192 + o] = a1 + red[1 * 128 + o] + ob;
      feat[(size_t)(t0 + 2) * 192 + o] = a2 + red[2 * 128 + o] + ob;
      feat[(size_t)(t0 + 3) * 192 + o] = a3 + red[3 * 128 + o] + ob;
    }
  }
  if (tid < 64) {
    int t = tid >> 4, f = tid & 15;
    int ti = t0 + t;
    float px = own_pos[ti * 2 + 0] / 25.f, py = own_pos[ti * 2 + 1] / 25.f;
    float pe = pos_b[f] + px * pos_w[f * 2 + 0] + py * pos_w[f * 2 + 1];
    float o0 = opponent[ti * 3 + 0] / 25.f, o1 = opponent[ti * 3 + 1] / 25.f, o2 = opponent[ti * 3 + 2] / 150.f;
    float oe = opp_b[f] + o0 * opp_w[f * 3 + 0] + o1 * opp_w[f * 3 + 1] + o2 * opp_w[f * 3 + 2];
    float ae = act_emb[action[ti] * 16 + f];
    size_t fb = (size_t)ti * 192;
    feat[fb + 128 + f] = pe;
    feat[fb + 144 + f] = oe;
    feat[fb + 160 + f] = ae;
    if (f == 0) feat[fb + 176] = cost[ti];
    if (f < 15) feat[fb + 177 + f] = 0.f;
  }
}

// ---------------- fp32 tiled GEMM (layer-0 input projection, unchanged) ----------------
__global__ __launch_bounds__(256) void gemm_bias_kernel(
    const float* __restrict__ A, const float* __restrict__ B,
    const float* __restrict__ bias, float* __restrict__ C,
    int M, int N, int K) {
  __shared__ __align__(16) float As[32][68];
  __shared__ __align__(16) float Bs[32][68];
  int tid = threadIdx.x;
  int mb = M >> 6;
  int bm = blockIdx.x & (mb - 1);
  int bn = blockIdx.x / mb;
  int tx = tid & 15, ty = tid >> 4;
  float acc[4][4];
#pragma unroll
  for (int i = 0; i < 4; i++)
#pragma unroll
    for (int j = 0; j < 4; j++) acc[i][j] = 0.f;
  for (int k0 = 0; k0 < K; k0 += 32) {
#pragma unroll
    for (int i = 0; i < 2; ++i) {
      int id = tid + i * 256;
      int m = id >> 3, kq = id & 7;
      float4 v = *(const float4*)&A[(size_t)(bm * 64 + m) * K + k0 + kq * 4];
      As[kq * 4 + 0][m] = v.x; As[kq * 4 + 1][m] = v.y; As[kq * 4 + 2][m] = v.z; As[kq * 4 + 3][m] = v.w;
    }
#pragma unroll
    for (int i = 0; i < 2; ++i) {
      int id = tid + i * 256;
      int k = id >> 4, nq = id & 15;
      float4 v = *(const float4*)&B[(size_t)(k0 + k) * N + bn * 64 + nq * 4];
      *(float4*)&Bs[k][nq * 4] = v;
    }
    __syncthreads();
#pragma unroll
    for (int k = 0; k < 32; ++k) {
      float4 a4 = *(const float4*)&As[k][ty * 4];
      float4 b4 = *(const float4*)&Bs[k][tx * 4];
      float am[4] = {a4.x, a4.y, a4.z, a4.w};
      float bn4[4] = {b4.x, b4.y, b4.z, b4.w};
#pragma unroll
      for (int i = 0; i < 4; i++)
#pragma unroll
        for (int j = 0; j < 4; j++) acc[i][j] += am[i] * bn4[j];
    }
    __syncthreads();
  }
#pragma unroll
  for (int i = 0; i < 4; ++i) {
    int m = bm * 64 + ty * 4 + i;
    int n0 = bn * 64 + tx * 4;
    float4 o;
    o.x = acc[i][0] + bias[n0 + 0];
    o.y = acc[i][1] + bias[n0 + 1];
    o.z = acc[i][2] + bias[n0 + 2];
    o.w = acc[i][3] + bias[n0 + 3];
    *(float4*)&C[(size_t)m * N + n0] = o;
  }
}

// ---------------- pipelined 2-layer LSTM: wg0=L0, wg1=L1, wg2..5=GEMM workers ----------------
// Round-10: non-volatile MFMA asm (scheduler may interleave loads) + depth-1
// software pipeline of the per-kb LDS weight reads (bf/f6/f7 prefetched one
// block ahead) -> the ~120cy ds_read latency no longer sits exposed between
// volatile-pinned MFMA batches.
__device__ __forceinline__ float sigf(float x) {
  return __builtin_amdgcn_rcpf(1.f + __expf(-x));
}

#define RAW_BAR() asm volatile("s_waitcnt lgkmcnt(0)\n\ts_barrier" ::: "memory")

#define SMEM_BYTES 136192
// LSTM layout: wlds 0..131071, hlds 131072..132095, zgu 132096..136191
// worker: hsl 0..32767

#define MFMA_AG(ACC, RS, RE, B) \
  asm("v_mfma_f32_16x16x32_f16 %0, a[" #RS ":" #RE "], %1, %0" \
      : "+v"(ACC) : "v"(B))

#define MFMA_VV(ACC, A, B) \
  asm("v_mfma_f32_16x16x32_f16 %0, %1, %2, %0" \
      : "+v"(ACC) : "v"(A), "v"(B))

#define AGINIT(RBI, KB, N0, N1, N2, N3) do { \
  int4v wv_ = *(const int4v*)&wfrag[((((size_t)(wave * 8 + RBI)) * 8 + KB) * 64 + lane) * 8]; \
  asm volatile("v_accvgpr_write_b32 a" #N0 ", %0\n\t" \
               "v_accvgpr_write_b32 a" #N1 ", %1\n\t" \
               "v_accvgpr_write_b32 a" #N2 ", %2\n\t" \
               "v_accvgpr_write_b32 a" #N3 ", %3" \
               :: "v"(wv_.x), "v"(wv_.y), "v"(wv_.z), "v"(wv_.w) \
               : "a" #N0, "a" #N1, "a" #N2, "a" #N3); } while (0)

#define SLDO(KB) (*(const half8*)(sbase + KB * 512 + sofs))

// prefetch next block's operands, then run current block's 8 MFMAs
#define KB_BLOCK(KBC, NXT, B0S, B0E, B1S, B1E, B2S, B2E, B3S, B3E, SV) do { \
  half8 bfn = *(const half8*)(hb + (NXT) * 32); \
  half8 f6n = *(const half8*)(wbase + (NXT) * 512 + tofs); \
  half8 f7n = *(const half8*)(wbase + (8 + (NXT)) * 512 + tofs); \
  MFMA_AG(acc0, B0S, B0E, bfc); \
  MFMA_AG(acc1, B1S, B1E, bfc); \
  MFMA_AG(acc2, B2S, B2E, bfc); \
  MFMA_AG(acc3, B3S, B3E, bfc); \
  MFMA_VV(acc4, wfv[KBC], bfc); \
  MFMA_VV(acc5, SV, bfc); \
  MFMA_VV(acc6, f6c, bfc); \
  MFMA_VV(acc7, f7c, bfc); \
  bfc = bfn; f6c = f6n; f7c = f7n; } while (0)

__device__ __forceinline__ void lstm_layer_run(
    const float* pre, const _Float16* wfrag, float* hs_out,
    float* hfin, float* cfin, int write_hs, int role,
    unsigned* flag0, unsigned* flag1, char* smem) {
  _Float16* wlds = (_Float16*)smem;                // [8w][2rb][8kb][64][8]
  _Float16* hlds = (_Float16*)(smem + 131072);     // [2][256]
  float*    zgu  = (float*)(smem + 132096);        // [256][4]

  int tid = threadIdx.x;
  int wave = tid >> 6, lane = tid & 63;
  int q = lane >> 4;
  int act = ((lane & 15) == 0);

  // ---- AGPR stash: rb0..3 -> physical a0..a127 (base = kb*16 + rbi*4) ----
  AGINIT(0, 0,   0,   1,   2,   3); AGINIT(1, 0,   4,   5,   6,   7);
  AGINIT(2, 0,   8,   9,  10,  11); AGINIT(3, 0,  12,  13,  14,  15);
  AGINIT(0, 1,  16,  17,  18,  19); AGINIT(1, 1,  20,  21,  22,  23);
  AGINIT(2, 1,  24,  25,  26,  27); AGINIT(3, 1,  28,  29,  30,  31);
  AGINIT(0, 2,  32,  33,  34,  35); AGINIT(1, 2,  36,  37,  38,  39);
  AGINIT(2, 2,  40,  41,  42,  43); AGINIT(3, 2,  44,  45,  46,  47);
  AGINIT(0, 3,  48,  49,  50,  51); AGINIT(1, 3,  52,  53,  54,  55);
  AGINIT(2, 3,  56,  57,  58,  59); AGINIT(3, 3,  60,  61,  62,  63);
  AGINIT(0, 4,  64,  65,  66,  67); AGINIT(1, 4,  68,  69,  70,  71);
  AGINIT(2, 4,  72,  73,  74,  75); AGINIT(3, 4,  76,  77,  78,  79);
  AGINIT(0, 5,  80,  81,  82,  83); AGINIT(1, 5,  84,  85,  86,  87);
  AGINIT(2, 5,  88,  89,  90,  91); AGINIT(3, 5,  92,  93,  94,  95);
  AGINIT(0, 6,  96,  97,  98,  99); AGINIT(1, 6, 100, 101, 102, 103);
  AGINIT(2, 6, 104, 105, 106, 107); AGINIT(3, 6, 108, 109, 110, 111);
  AGINIT(0, 7, 112, 113, 114, 115); AGINIT(1, 7, 116, 117, 118, 119);
  AGINIT(2, 7, 120, 121, 122, 123); AGINIT(3, 7, 124, 125, 126, 127);

  // VGPR-resident: rb4
  half8 wfv[8];
#pragma unroll
  for (int kb = 0; kb < 8; ++kb)
    wfv[kb] = *(const half8*)&wfrag[((((size_t)(wave * 8 + 4)) * 8 + kb) * 64 + lane) * 8];

  // LDS-resident: rb6, rb7
#pragma unroll
  for (int p = 0; p < 2; ++p)
#pragma unroll
    for (int kb = 0; kb < 8; ++kb) {
      half8 v = *(const half8*)&wfrag[((((size_t)(wave * 8 + 6 + p)) * 8 + kb) * 64 + lane) * 8];
      *(half8*)&wlds[(((wave * 2 + p) * 8 + kb) * 64 + lane) * 8] = v;
    }

  if (tid < 256) { hlds[tid] = (_Float16)0.f; hlds[256 + tid] = (_Float16)0.f; }
  __syncthreads();

  const _Float16* wbase = &wlds[(size_t)wave * 8192 + lane * 8];
  const _Float16* sbase = &wfrag[(((size_t)(wave * 8 + 5)) * 4096) + lane * 8];
  float c = 0.f;
  // stream ring prologue (rb5, kb 0..2)
  half8 s0 = *(const half8*)(sbase + 0 * 512);
  half8 s1 = *(const half8*)(sbase + 1 * 512);
  half8 s2 = *(const half8*)(sbase + 2 * 512);

  for (int t = 0; t < T_LEN; ++t) {
    // consumer: acquire this chunk's pre before touching it
    if (role == 1 && (t & (CHUNK - 1)) == 0) {
      if (tid == 0) {
        while (__hip_atomic_load(&flag1[t >> CHUNK_LOG], __ATOMIC_ACQUIRE,
                                 __HIP_MEMORY_SCOPE_AGENT) < (unsigned)NW)
          __builtin_amdgcn_s_sleep(8);
      }
      __syncthreads();
      __builtin_amdgcn_fence(__ATOMIC_ACQUIRE, "agent");
    }

    int tofs = 0, sofs = 0;
    asm volatile("" : "+v"(tofs), "+v"(sofs));   // defeat LICM/CSE of weight reloads
    f32x4 pv = {0.f, 0.f, 0.f, 0.f};
    if (tid < 256) pv = *(const f32x4*)&pre[(size_t)t * 1024 + tid * 4];
    const _Float16* hb = &hlds[(t & 1) * 256 + q * 8];
    f32x4 acc0 = {0.f,0.f,0.f,0.f}, acc1 = {0.f,0.f,0.f,0.f};
    f32x4 acc2 = {0.f,0.f,0.f,0.f}, acc3 = {0.f,0.f,0.f,0.f};
    f32x4 acc4 = {0.f,0.f,0.f,0.f}, acc5 = {0.f,0.f,0.f,0.f};
    f32x4 acc6 = {0.f,0.f,0.f,0.f}, acc7 = {0.f,0.f,0.f,0.f};

    // software-pipeline prologue: kb=0 operands
    half8 bfc = *(const half8*)(hb);
    half8 f6c = *(const half8*)(wbase + tofs);
    half8 f7c = *(const half8*)(wbase + 8 * 512 + tofs);

    KB_BLOCK(0, 1,   0,   3,   4,   7,   8,  11,  12,  15, s0); s0 = SLDO(3);
    KB_BLOCK(1, 2,  16,  19,  20,  23,  24,  27,  28,  31, s1); s1 = SLDO(4);
    KB_BLOCK(2, 3,  32,  35,  36,  39,  40,  43,  44,  47, s2); s2 = SLDO(5);
    KB_BLOCK(3, 4,  48,  51,  52,  55,  56,  59,  60,  63, s0); s0 = SLDO(6);
    KB_BLOCK(4, 5,  64,  67,  68,  71,  72,  75,  76,  79, s1); s1 = SLDO(7);
    KB_BLOCK(5, 6,  80,  83,  84,  87,  88,  91,  92,  95, s2);
    KB_BLOCK(6, 7,  96,  99, 100, 103, 104, 107, 108, 111, s0);
    KB_BLOCK(7, 0, 112, 115, 116, 119, 120, 123, 124, 127, s1);

    if (act) {
      float* zb = &zgu[wave * 128 + q * 4];
      *(f32x4*)(zb + 0 * 16) = acc0;
      *(f32x4*)(zb + 1 * 16) = acc1;
      *(f32x4*)(zb + 2 * 16) = acc2;
      *(f32x4*)(zb + 3 * 16) = acc3;
      *(f32x4*)(zb + 4 * 16) = acc4;
      *(f32x4*)(zb + 5 * 16) = acc5;
      *(f32x4*)(zb + 6 * 16) = acc6;
      *(f32x4*)(zb + 7 * 16) = acc7;
    }
    RAW_BAR();                 // lgkmcnt-only: zgu visible, globals stay in flight
    // refill stream ring for next step (latency hidden under gate phase)
    s0 = SLDO(0); s1 = SLDO(1); s2 = SLDO(2);
    if (tid < 256) {
      f32x4 zv = *(const f32x4*)&zgu[(size_t)tid * 4];
      float zi = zv.x + pv.x;
      float zf = zv.y + pv.y;
      float zt = zv.z + pv.z;
      float zo = zv.w + pv.w;
      float ig = sigf(zi);
      float fg = sigf(zf);
      float gg = 2.f * sigf(2.f * zt) - 1.f;
      float og = sigf(zo);
      c = fg * c + ig * gg;
      float hn = og * (2.f * sigf(2.f * c) - 1.f);
      hlds[((t + 1) & 1) * 256 + tid] = (_Float16)hn;
      if (write_hs) hs_out[(size_t)t * 256 + tid] = hn;
      if (t == T_LEN - 1) { hfin[tid] = hn; cfin[tid] = c; }
    }
    RAW_BAR();                 // lgkmcnt-only: h(t+1) visible for next step's bf

    // producer: publish finished chunk (vmcnt drain + agent release)
    if (role == 0 && (t & (CHUNK - 1)) == (CHUNK - 1)) {
      asm volatile("s_waitcnt vmcnt(0)" ::: "memory");
      __syncthreads();
      if (tid == 0) {
        __builtin_amdgcn_fence(__ATOMIC_RELEASE, "agent");
        __hip_atomic_store(&flag0[t >> CHUNK_LOG], 1u, __ATOMIC_RELEASE,
                           __HIP_MEMORY_SCOPE_AGENT);
      }
    }
  }
}

__device__ __forceinline__ void gemm_worker_run(
    const float* hs0, float* pre, const float* wih1T, const float* bias1,
    unsigned* flag0, unsigned* flag1, int w, char* smem) {
  float* hsl = (float*)smem;   // [32][256] = 32 KB
  int tid = threadIdx.x;
  for (int cnk = 0; cnk < NCHUNK; ++cnk) {
    if (tid == 0) {
      while (__hip_atomic_load(&flag0[cnk], __ATOMIC_ACQUIRE,
                               __HIP_MEMORY_SCOPE_AGENT) == 0u)
        __builtin_amdgcn_s_sleep(8);
    }
    __syncthreads();
    __builtin_amdgcn_fence(__ATOMIC_ACQUIRE, "agent");
    int r0 = cnk * CHUNK + w * 32;
    for (int i = tid; i < 32 * 256; i += 512)
      hsl[i] = hs0[(size_t)(r0 + (i >> 8)) * 256 + (i & 255)];
    __syncthreads();
    for (int half = 0; half < 2; ++half) {
      int p = half * 512 + tid;
      float bv = bias1[p];
      for (int rb = 0; rb < 4; ++rb) {
        float accw[8];
#pragma unroll
        for (int r = 0; r < 8; ++r) accw[r] = bv;
        for (int k = 0; k < 256; ++k) {
          float wv = wih1T[k * 1024 + p];
#pragma unroll
          for (int r = 0; r < 8; ++r)
            accw[r] += hsl[(rb * 8 + r) * 256 + k] * wv;
        }
#pragma unroll
        for (int r = 0; r < 8; ++r)
          pre[(size_t)(r0 + rb * 8 + r) * 1024 + p] = accw[r];
      }
    }
    asm volatile("s_waitcnt vmcnt(0)" ::: "memory");
    __syncthreads();
    if (tid == 0) {
      __builtin_amdgcn_fence(__ATOMIC_RELEASE, "agent");
      __hip_atomic_fetch_add(&flag1[cnk], 1u, __ATOMIC_RELEASE,
                             __HIP_MEMORY_SCOPE_AGENT);
    }
    __syncthreads();
  }
}

__global__ __launch_bounds__(512) void lstm_pipe_kernel(
    float* pre,                       // [T][1024]: L0 input (pre0); workers overwrite with pre1
    const _Float16* wfrag,            // [2][64][8][64][8]
    float* hs0,
    float* h0f, float* c0f, float* h1f, float* c1f,
    const float* wih1T, const float* bias1,
    unsigned* flags) {                // flags[0..127]=flag0, [128..255]=flag1
  extern __shared__ __align__(16) char smem[];
  unsigned* flag0 = flags;
  unsigned* flag1 = flags + NCHUNK;
  int bid = blockIdx.x;
  if (bid == 0) {
    lstm_layer_run(pre, wfrag, hs0, h0f, c0f, 1, 0, flag0, flag1, smem);
  } else if (bid == 1) {
    lstm_layer_run(pre, wfrag + 262144, nullptr, h1f, c1f, 0, 1, flag0, flag1, smem);
  } else {
    gemm_worker_run(hs0, pre, wih1T, bias1, flag0, flag1, bid - 2, smem);
  }
}

// ---------------- gather outputs ----------------
__global__ void finalize_kernel(const float* __restrict__ h0, const float* __restrict__ c0,
                                const float* __restrict__ h1, const float* __restrict__ c1,
                                float* __restrict__ out) {
  int i = blockIdx.x * blockDim.x + threadIdx.x;
  if (i < 256) out[i] = h1[i];
  else if (i < 512) out[i] = h0[i - 256];
  else if (i < 768) out[i] = h1[i - 512];
  else if (i < 1024) out[i] = c0[i - 768];
  else if (i < 1280) out[i] = c1[i - 1024];
}

extern "C" void kernel_launch(void* const* d_in, const int* in_sizes, int n_in,
                              void* d_out, int out_size, void* d_ws, size_t ws_size,
                              hipStream_t stream) {
  const float* fov      = (const float*)d_in[0];
  const float* own_pos  = (const float*)d_in[1];
  const float* opponent = (const float*)d_in[2];
  const float* cost     = (const float*)d_in[3];
  const int*   action   = (const int*)d_in[4];
  const float* conv1_w  = (const float*)d_in[5];
  const float* conv1_b  = (const float*)d_in[6];
  const float* conv2_w  = (const float*)d_in[7];
  const float* conv2_b  = (const float*)d_in[8];
  const float* obs_w    = (const float*)d_in[9];
  const float* obs_b    = (const float*)d_in[10];
  const float* pos_w    = (const float*)d_in[11];
  const float* pos_b    = (const float*)d_in[12];
  const float* opp_w    = (const float*)d_in[13];
  const float* opp_b    = (const float*)d_in[14];
  const float* act_emb  = (const float*)d_in[15];
  const float* wih0     = (const float*)d_in[16];
  const float* whh0     = (const float*)d_in[17];
  const float* bih0     = (const float*)d_in[18];
  const float* bhh0     = (const float*)d_in[19];
  const float* wih1     = (const float*)d_in[20];
  const float* whh1     = (const float*)d_in[21];
  const float* bih1     = (const float*)d_in[22];
  const float* bhh1     = (const float*)d_in[23];

  char* ws = (char*)d_ws;
  size_t off = 0;
  auto alloc = [&](size_t bytes) {
    void* p = ws + off;
    off += (bytes + 255) & ~(size_t)255;
    return p;
  };
  float* feat   = (float*)alloc((size_t)T_LEN * 192 * 4);
  float* pre    = (float*)alloc((size_t)T_LEN * 1024 * 4);
  float* hs0    = (float*)alloc((size_t)T_LEN * 256 * 4);
  float* obs_wT = (float*)alloc(1600 * 128 * 4);
  float* wih0T  = (float*)alloc(192 * 1024 * 4);
  float* wih1T  = (float*)alloc(256 * 1024 * 4);
  _Float16* wfrag = (_Float16*)alloc((size_t)2 * 262144 * 2);
  float* bias0  = (float*)alloc(1024 * 4);
  float* bias1  = (float*)alloc(1024 * 4);
  float* h0f = (float*)alloc(256 * 4);
  float* c0f = (float*)alloc(256 * 4);
  float* h1f = (float*)alloc(256 * 4);
  float* c1f = (float*)alloc(256 * 4);
  unsigned* flags = (unsigned*)alloc(2 * NCHUNK * 4);

  static int lds_attr_set = 0;
  if (!lds_attr_set) {
    hipFuncSetAttribute((const void*)lstm_pipe_kernel,
                        hipFuncAttributeMaxDynamicSharedMemorySize, SMEM_BYTES);
    lds_attr_set = 1;
  }

  prep_kernel<<<2048, 256, 0, stream>>>(obs_w, wih0, wih1, whh0, whh1,
                                        bih0, bhh0, bih1, bhh1,
                                        obs_wT, wih0T, wih1T, wfrag, bias0, bias1);
  encoder_kernel<<<T_LEN / ETS, 256, 0, stream>>>(fov, own_pos, opponent, cost, action,
      conv1_w, conv1_b, conv2_w, conv2_b, obs_wT, obs_b, pos_w, pos_b, opp_w, opp_b,
      act_emb, feat);
  gemm_bias_kernel<<<4096, 256, 0, stream>>>(feat, wih0T, bias0, pre, T_LEN, 1024, 192);
  hipMemsetAsync(flags, 0, 2 * NCHUNK * 4, stream);
  lstm_pipe_kernel<<<2 + NW, 512, SMEM_BYTES, stream>>>(
      pre, wfrag, hs0, h0f, c0f, h1f, c1f, wih1T, bias1, flags);
  finalize_kernel<<<5, 256, 0, stream>>>(h0f, c0f, h1f, c1f, (float*)d_out);
}

// Round 11
// 28128.445 us; speedup vs baseline: 1.2402x; 1.2402x over previous
//
#include <hip/hip_runtime.h>
#include <hip/hip_bf16.h>
#include <cstdint>
#include <cstddef>

#define T_LEN 16384
#define ETS 4
#define C1T 1796
#define CHUNK 128
#define CHUNK_LOG 7
#define NCHUNK (T_LEN / CHUNK)
#define NW 4

typedef _Float16 half8 __attribute__((ext_vector_type(8)));
typedef float f32x4 __attribute__((ext_vector_type(4)));
typedef int int4v __attribute__((ext_vector_type(4)));

// ---------------- prep: transposes + bias sums + f16 MFMA weight fragments ----------------
// Row permutation: p = 4*u + g  ->  orig row = g*256 + u
__global__ void prep_kernel(const float* __restrict__ obs_w,
                            const float* __restrict__ wih0,
                            const float* __restrict__ wih1,
                            const float* __restrict__ whh0,
                            const float* __restrict__ whh1,
                            const float* __restrict__ bih0, const float* __restrict__ bhh0,
                            const float* __restrict__ bih1, const float* __restrict__ bhh1,
                            float* __restrict__ obs_wT,    // [1600][128]
                            float* __restrict__ wih0T,     // [192][1024] permuted cols, zero-pad k>=177
                            float* __restrict__ wih1T,     // [256][1024] permuted cols
                            _Float16* __restrict__ wfrag,  // [2][64rb][8kb][64lane][8]
                            float* __restrict__ bias0, float* __restrict__ bias1) {
  int i = blockIdx.x * blockDim.x + threadIdx.x;   // 2048*256 = 524288 threads
  {
    int layer = i >> 18;
    int r = i & 262143;
    int rb = r >> 12;
    int kb = (r >> 9) & 7;
    int lane = (r >> 3) & 63;
    int j = r & 7;
    int row_p = rb * 16 + (lane & 15);
    int k = kb * 32 + (lane >> 4) * 8 + j;
    int orig = (row_p & 3) * 256 + (row_p >> 2);
    const float* src = layer ? whh1 : whh0;
    wfrag[i] = (_Float16)src[orig * 256 + k];
  }
  if (i < 1600 * 128) { int k = i >> 7, o = i & 127; obs_wT[i] = obs_w[o * 1600 + k]; }
  if (i < 192 * 1024) {
    int k = i >> 10, p = i & 1023;
    int orig = (p & 3) * 256 + (p >> 2);
    wih0T[i] = (k < 177) ? wih0[orig * 177 + k] : 0.f;
  }
  if (i < 256 * 1024) {
    int k = i >> 10, p = i & 1023;
    int orig = (p & 3) * 256 + (p >> 2);
    wih1T[i] = wih1[orig * 256 + k];
  }
  if (i < 1024) {
    int orig = (i & 3) * 256 + (i >> 2);
    bias0[i] = bih0[orig] + bhh0[orig];
    bias1[i] = bih1[orig] + bhh1[orig];
  }
}

// ---------------- encoder (unchanged, verified) ----------------
__global__ __launch_bounds__(256) void encoder_kernel(
    const float* __restrict__ fov, const float* __restrict__ own_pos,
    const float* __restrict__ opponent, const float* __restrict__ cost,
    const int* __restrict__ action,
    const float* __restrict__ w1, const float* __restrict__ b1,
    const float* __restrict__ w2, const float* __restrict__ b2,
    const float* __restrict__ obs_wT, const float* __restrict__ obs_b,
    const float* __restrict__ pos_w, const float* __restrict__ pos_b,
    const float* __restrict__ opp_w, const float* __restrict__ opp_b,
    const float* __restrict__ act_emb,
    float* __restrict__ feat) {
  __shared__ float w1s[864];
  __shared__ float b1s[32];
  __shared__ float inp[ETS * 3 * 7 * 7];
  __shared__ __align__(16) float c1[ETS * C1T];
  __shared__ __align__(16) float c2s[1600 * ETS];
  __shared__ float red[4 * 128];
  int tid = threadIdx.x;
  int t0 = blockIdx.x * ETS;

  for (int i = tid; i < 864; i += 256) w1s[i] = w1[i];
  if (tid < 32) b1s[tid] = b1[tid];
  for (int i = tid; i < ETS * 3 * 49; i += 256) inp[i] = 0.f;
  for (int i = tid; i < ETS * C1T; i += 256) c1[i] = 0.f;
  __syncthreads();
  for (int i = tid; i < ETS * 75; i += 256) {
    int t = i / 75, r = i % 75;
    int y = r / 15, x = (r / 3) % 5, ch = r % 3;
    inp[((t * 3 + ch) * 7 + (y + 1)) * 7 + (x + 1)] = fov[(size_t)(t0 + t) * 75 + r];
  }
  __syncthreads();
  for (int i = tid; i < ETS * 800; i += 256) {
    int t = i / 800, r = i % 800;
    int oc = r / 25, p = r % 25, y = p / 5, x = p % 5;
    float s = b1s[oc];
#pragma unroll
    for (int ch = 0; ch < 3; ++ch)
#pragma unroll
      for (int ky = 0; ky < 3; ++ky)
#pragma unroll
        for (int kx = 0; kx < 3; ++kx)
          s += inp[((t * 3 + ch) * 7 + y + ky) * 7 + x + kx] * w1s[oc * 27 + ch * 9 + ky * 3 + kx];
    c1[t * C1T + (oc * 7 + y + 1) * 8 + (x + 1)] = fmaxf(s, 0.f);
  }
  __syncthreads();
  {
    int oc = tid >> 2, tt = tid & 3;
    float acc[25];
    float bv = b2[oc];
#pragma unroll
    for (int p = 0; p < 25; ++p) acc[p] = bv;
    for (int ic = 0; ic < 32; ++ic) {
      float pl[56];
      const float* base = &c1[tt * C1T + ic * 56];
#pragma unroll
      for (int qq = 0; qq < 14; ++qq) {
        float4 v = *(const float4*)(base + qq * 4);
        pl[qq * 4 + 0] = v.x; pl[qq * 4 + 1] = v.y; pl[qq * 4 + 2] = v.z; pl[qq * 4 + 3] = v.w;
      }
      const float* wrow = &w2[(size_t)(oc * 32 + ic) * 9];
#pragma unroll
      for (int ky = 0; ky < 3; ++ky)
#pragma unroll
        for (int kx = 0; kx < 3; ++kx) {
          float wv = wrow[ky * 3 + kx];
#pragma unroll
          for (int p = 0; p < 25; ++p) {
            int y = p / 5, x = p % 5;
            acc[p] += pl[(y + ky) * 8 + (x + kx)] * wv;
          }
        }
    }
#pragma unroll
    for (int p = 0; p < 25; ++p)
      c2s[(oc * 25 + p) * ETS + tt] = fmaxf(acc[p], 0.f);
  }
  __syncthreads();
  {
    int o = tid & 127, kh = tid >> 7;
    float a0 = 0, a1 = 0, a2 = 0, a3 = 0;
    for (int k = kh * 800; k < kh * 800 + 800; ++k) {
      float wv = obs_wT[k * 128 + o];
      float4 cv = *(const float4*)&c2s[k * ETS];
      a0 += cv.x * wv; a1 += cv.y * wv; a2 += cv.z * wv; a3 += cv.w * wv;
    }
    if (kh == 1) { red[0 * 128 + o] = a0; red[1 * 128 + o] = a1; red[2 * 128 + o] = a2; red[3 * 128 + o] = a3; }
    __syncthreads();
    if (kh == 0) {
      float ob = obs_b[o];
      feat[(size_t)(t0 + 0) * 192 + o] = a0 + red[0 * 128 + o] + ob;
      feat[(size_t)(t0 + 1) * 192 + o] = a1 + red[1 * 128 + o] + ob;
      feat[(size_t)(t0 + 2) * 192 + o] = a2 + red[2 * 128 + o] + ob;
      feat[(size_t)(t0 + 3) * 192 + o] = a3 + red[3 * 128 + o] + ob;
    }
  }
  if (tid < 64) {
    int t = tid >> 4, f = tid & 15;
    int ti = t0 + t;
    float px = own_pos[ti * 2 + 0] / 25.f, py = own_pos[ti * 2 + 1] / 25.f;
    float pe = pos_b[f] + px * pos_w[f * 2 + 0] + py * pos_w[f * 2 + 1];
    float o0 = opponent[ti * 3 + 0] / 25.f, o1 = opponent[ti * 3 + 1] / 25.f, o2 = opponent[ti * 3 + 2] / 150.f;
    float oe = opp_b[f] + o0 * opp_w[f * 3 + 0] + o1 * opp_w[f * 3 + 1] + o2 * opp_w[f * 3 + 2];
    float ae = act_emb[action[ti] * 16 + f];
    size_t fb = (size_t)ti * 192;
    feat[fb + 128 + f] = pe;
    feat[fb + 144 + f] = oe;
    feat[fb + 160 + f] = ae;
    if (f == 0) feat[fb + 176] = cost[ti];
    if (f < 15) feat[fb + 177 + f] = 0.f;
  }
}

// ---------------- fp32 tiled GEMM (layer-0 input projection, unchanged) ----------------
__global__ __launch_bounds__(256) void gemm_bias_kernel(
    const float* __restrict__ A, const float* __restrict__ B,
    const float* __restrict__ bias, float* __restrict__ C,
    int M, int N, int K) {
  __shared__ __align__(16) float As[32][68];
  __shared__ __align__(16) float Bs[32][68];
  int tid = threadIdx.x;
  int mb = M >> 6;
  int bm = blockIdx.x & (mb - 1);
  int bn = blockIdx.x / mb;
  int tx = tid & 15, ty = tid >> 4;
  float acc[4][4];
#pragma unroll
  for (int i = 0; i < 4; i++)
#pragma unroll
    for (int j = 0; j < 4; j++) acc[i][j] = 0.f;
  for (int k0 = 0; k0 < K; k0 += 32) {
#pragma unroll
    for (int i = 0; i < 2; ++i) {
      int id = tid + i * 256;
      int m = id >> 3, kq = id & 7;
      float4 v = *(const float4*)&A[(size_t)(bm * 64 + m) * K + k0 + kq * 4];
      As[kq * 4 + 0][m] = v.x; As[kq * 4 + 1][m] = v.y; As[kq * 4 + 2][m] = v.z; As[kq * 4 + 3][m] = v.w;
    }
#pragma unroll
    for (int i = 0; i < 2; ++i) {
      int id = tid + i * 256;
      int k = id >> 4, nq = id & 15;
      float4 v = *(const float4*)&B[(size_t)(k0 + k) * N + bn * 64 + nq * 4];
      *(float4*)&Bs[k][nq * 4] = v;
    }
    __syncthreads();
#pragma unroll
    for (int k = 0; k < 32; ++k) {
      float4 a4 = *(const float4*)&As[k][ty * 4];
      float4 b4 = *(const float4*)&Bs[k][tx * 4];
      float am[4] = {a4.x, a4.y, a4.z, a4.w};
      float bn4[4] = {b4.x, b4.y, b4.z, b4.w};
#pragma unroll
      for (int i = 0; i < 4; i++)
#pragma unroll
        for (int j = 0; j < 4; j++) acc[i][j] += am[i] * bn4[j];
    }
    __syncthreads();
  }
#pragma unroll
  for (int i = 0; i < 4; ++i) {
    int m = bm * 64 + ty * 4 + i;
    int n0 = bn * 64 + tx * 4;
    float4 o;
    o.x = acc[i][0] + bias[n0 + 0];
    o.y = acc[i][1] + bias[n0 + 1];
    o.z = acc[i][2] + bias[n0 + 2];
    o.w = acc[i][3] + bias[n0 + 3];
    *(float4*)&C[(size_t)m * N + n0] = o;
  }
}

// ---------------- pipelined 2-layer LSTM: wg0=L0, wg1=L1, wg2..5=GEMM workers ----------------
// Round-11 (on r9 base; r10 reverted): the zgu gate-exchange is WAVE-LOCAL
// (wave w's MFMAs produce gates only for units w*32..w*32+31), so barrier #1
// is replaced by a wave-local s_waitcnt lgkmcnt(0). Gate phase runs in lanes
// 0..31 of EVERY wave (c-state lives there); only ONE barrier per step remains
// (h-write -> h-read, double-buffered hlds).
__device__ __forceinline__ float sigf(float x) {
  return __builtin_amdgcn_rcpf(1.f + __expf(-x));
}

#define RAW_BAR() asm volatile("s_waitcnt lgkmcnt(0)\n\ts_barrier" ::: "memory")
#define LGKM_DRAIN() asm volatile("s_waitcnt lgkmcnt(0)" ::: "memory")

#define SMEM_BYTES 136192
// LSTM layout: wlds 0..131071, hlds 131072..132095, zgu 132096..136191
// worker: hsl 0..32767

#define MFMA_AG(ACC, RS, RE, B) \
  asm volatile("v_mfma_f32_16x16x32_f16 %0, a[" #RS ":" #RE "], %1, %0" \
               : "+v"(ACC) : "v"(B))

#define MFMA_VV(ACC, A, B) \
  asm volatile("v_mfma_f32_16x16x32_f16 %0, %1, %2, %0" \
               : "+v"(ACC) : "v"(A), "v"(B))

#define AGINIT(RBI, KB, N0, N1, N2, N3) do { \
  int4v wv_ = *(const int4v*)&wfrag[((((size_t)(wave * 8 + RBI)) * 8 + KB) * 64 + lane) * 8]; \
  asm volatile("v_accvgpr_write_b32 a" #N0 ", %0\n\t" \
               "v_accvgpr_write_b32 a" #N1 ", %1\n\t" \
               "v_accvgpr_write_b32 a" #N2 ", %2\n\t" \
               "v_accvgpr_write_b32 a" #N3 ", %3" \
               :: "v"(wv_.x), "v"(wv_.y), "v"(wv_.z), "v"(wv_.w) \
               : "a" #N0, "a" #N1, "a" #N2, "a" #N3); } while (0)

#define SLDO(KB) (*(const half8*)(sbase + KB * 512 + sofs))

#define KB_BLOCK(KB, B0S, B0E, B1S, B1E, B2S, B2E, B3S, B3E, SV) do { \
  half8 bf = *(const half8*)(hb + KB * 32); \
  half8 f6 = *(const half8*)(wbase + KB * 512 + tofs); \
  half8 f7 = *(const half8*)(wbase + (8 + KB) * 512 + tofs); \
  MFMA_AG(acc0, B0S, B0E, bf); \
  MFMA_AG(acc1, B1S, B1E, bf); \
  MFMA_AG(acc2, B2S, B2E, bf); \
  MFMA_AG(acc3, B3S, B3E, bf); \
  MFMA_VV(acc4, wfv[KB], bf); \
  MFMA_VV(acc5, SV, bf); \
  MFMA_VV(acc6, f6, bf); \
  MFMA_VV(acc7, f7, bf); } while (0)

__device__ __forceinline__ void lstm_layer_run(
    const float* pre, const _Float16* wfrag, float* hs_out,
    float* hfin, float* cfin, int write_hs, int role,
    unsigned* flag0, unsigned* flag1, char* smem) {
  _Float16* wlds = (_Float16*)smem;                // [8w][2rb][8kb][64][8]
  _Float16* hlds = (_Float16*)(smem + 131072);     // [2][256]
  float*    zgu  = (float*)(smem + 132096);        // [8w][32u][4]

  int tid = threadIdx.x;
  int wave = tid >> 6, lane = tid & 63;
  int q = lane >> 4;
  int act = ((lane & 15) == 0);
  int gl = (lane < 32);                            // gate lane: unit u = wave*32+lane
  int u = wave * 32 + lane;                        // valid when gl

  // ---- AGPR stash: rb0..3 -> physical a0..a127 (base = kb*16 + rbi*4) ----
  AGINIT(0, 0,   0,   1,   2,   3); AGINIT(1, 0,   4,   5,   6,   7);
  AGINIT(2, 0,   8,   9,  10,  11); AGINIT(3, 0,  12,  13,  14,  15);
  AGINIT(0, 1,  16,  17,  18,  19); AGINIT(1, 1,  20,  21,  22,  23);
  AGINIT(2, 1,  24,  25,  26,  27); AGINIT(3, 1,  28,  29,  30,  31);
  AGINIT(0, 2,  32,  33,  34,  35); AGINIT(1, 2,  36,  37,  38,  39);
  AGINIT(2, 2,  40,  41,  42,  43); AGINIT(3, 2,  44,  45,  46,  47);
  AGINIT(0, 3,  48,  49,  50,  51); AGINIT(1, 3,  52,  53,  54,  55);
  AGINIT(2, 3,  56,  57,  58,  59); AGINIT(3, 3,  60,  61,  62,  63);
  AGINIT(0, 4,  64,  65,  66,  67); AGINIT(1, 4,  68,  69,  70,  71);
  AGINIT(2, 4,  72,  73,  74,  75); AGINIT(3, 4,  76,  77,  78,  79);
  AGINIT(0, 5,  80,  81,  82,  83); AGINIT(1, 5,  84,  85,  86,  87);
  AGINIT(2, 5,  88,  89,  90,  91); AGINIT(3, 5,  92,  93,  94,  95);
  AGINIT(0, 6,  96,  97,  98,  99); AGINIT(1, 6, 100, 101, 102, 103);
  AGINIT(2, 6, 104, 105, 106, 107); AGINIT(3, 6, 108, 109, 110, 111);
  AGINIT(0, 7, 112, 113, 114, 115); AGINIT(1, 7, 116, 117, 118, 119);
  AGINIT(2, 7, 120, 121, 122, 123); AGINIT(3, 7, 124, 125, 126, 127);

  // VGPR-resident: rb4
  half8 wfv[8];
#pragma unroll
  for (int kb = 0; kb < 8; ++kb)
    wfv[kb] = *(const half8*)&wfrag[((((size_t)(wave * 8 + 4)) * 8 + kb) * 64 + lane) * 8];

  // LDS-resident: rb6, rb7
#pragma unroll
  for (int p = 0; p < 2; ++p)
#pragma unroll
    for (int kb = 0; kb < 8; ++kb) {
      half8 v = *(const half8*)&wfrag[((((size_t)(wave * 8 + 6 + p)) * 8 + kb) * 64 + lane) * 8];
      *(half8*)&wlds[(((wave * 2 + p) * 8 + kb) * 64 + lane) * 8] = v;
    }

  if (tid < 256) { hlds[tid] = (_Float16)0.f; hlds[256 + tid] = (_Float16)0.f; }
  __syncthreads();

  const _Float16* wbase = &wlds[(size_t)wave * 8192 + lane * 8];
  const _Float16* sbase = &wfrag[(((size_t)(wave * 8 + 5)) * 4096) + lane * 8];
  float c = 0.f;
  // stream ring prologue (rb5, kb 0..2)
  half8 s0 = *(const half8*)(sbase + 0 * 512);
  half8 s1 = *(const half8*)(sbase + 1 * 512);
  half8 s2 = *(const half8*)(sbase + 2 * 512);

  for (int t = 0; t < T_LEN; ++t) {
    // consumer: acquire this chunk's pre before touching it
    if (role == 1 && (t & (CHUNK - 1)) == 0) {
      if (tid == 0) {
        while (__hip_atomic_load(&flag1[t >> CHUNK_LOG], __ATOMIC_ACQUIRE,
                                 __HIP_MEMORY_SCOPE_AGENT) < (unsigned)NW)
          __builtin_amdgcn_s_sleep(8);
      }
      __syncthreads();
      __builtin_amdgcn_fence(__ATOMIC_ACQUIRE, "agent");
    }

    int tofs = 0, sofs = 0;
    asm volatile("" : "+v"(tofs), "+v"(sofs));   // defeat LICM/CSE of weight reloads
    f32x4 pv = {0.f, 0.f, 0.f, 0.f};
    if (gl) pv = *(const f32x4*)&pre[(size_t)t * 1024 + u * 4];
    const _Float16* hb = &hlds[(t & 1) * 256 + q * 8];
    f32x4 acc0 = {0.f,0.f,0.f,0.f}, acc1 = {0.f,0.f,0.f,0.f};
    f32x4 acc2 = {0.f,0.f,0.f,0.f}, acc3 = {0.f,0.f,0.f,0.f};
    f32x4 acc4 = {0.f,0.f,0.f,0.f}, acc5 = {0.f,0.f,0.f,0.f};
    f32x4 acc6 = {0.f,0.f,0.f,0.f}, acc7 = {0.f,0.f,0.f,0.f};

    KB_BLOCK(0,   0,   3,   4,   7,   8,  11,  12,  15, s0); s0 = SLDO(3);
    KB_BLOCK(1,  16,  19,  20,  23,  24,  27,  28,  31, s1); s1 = SLDO(4);
    KB_BLOCK(2,  32,  35,  36,  39,  40,  43,  44,  47, s2); s2 = SLDO(5);
    KB_BLOCK(3,  48,  51,  52,  55,  56,  59,  60,  63, s0); s0 = SLDO(6);
    KB_BLOCK(4,  64,  67,  68,  71,  72,  75,  76,  79, s1); s1 = SLDO(7);
    KB_BLOCK(5,  80,  83,  84,  87,  88,  91,  92,  95, s2);
    KB_BLOCK(6,  96,  99, 100, 103, 104, 107, 108, 111, s0);
    KB_BLOCK(7, 112, 115, 116, 119, 120, 123, 124, 127, s1);

    // wave-local gate scatter: zgu[wave][rbi*4+q] = {i,f,g,o}
    if (act) {
      float* zb = &zgu[wave * 128 + q * 4];
      *(f32x4*)(zb + 0 * 16) = acc0;
      *(f32x4*)(zb + 1 * 16) = acc1;
      *(f32x4*)(zb + 2 * 16) = acc2;
      *(f32x4*)(zb + 3 * 16) = acc3;
      *(f32x4*)(zb + 4 * 16) = acc4;
      *(f32x4*)(zb + 5 * 16) = acc5;
      *(f32x4*)(zb + 6 * 16) = acc6;
      *(f32x4*)(zb + 7 * 16) = acc7;
    }
    LGKM_DRAIN();              // wave-local: own zgu writes complete (no barrier)
    // refill stream ring for next step (latency hidden under gate phase)
    s0 = SLDO(0); s1 = SLDO(1); s2 = SLDO(2);
    if (gl) {
      f32x4 zv = *(const f32x4*)&zgu[(size_t)(wave * 128 + lane * 4)];
      float zi = zv.x + pv.x;
      float zf = zv.y + pv.y;
      float zt = zv.z + pv.z;
      float zo = zv.w + pv.w;
      float ig = sigf(zi);
      float fg = sigf(zf);
      float gg = 2.f * sigf(2.f * zt) - 1.f;
      float og = sigf(zo);
      c = fg * c + ig * gg;
      float hn = og * (2.f * sigf(2.f * c) - 1.f);
      hlds[((t + 1) & 1) * 256 + u] = (_Float16)hn;
      if (write_hs) hs_out[(size_t)t * 256 + u] = hn;
      if (t == T_LEN - 1) { hfin[u] = hn; cfin[u] = c; }
    }
    RAW_BAR();                 // single per-step barrier: h(t+1) visible to all waves

    // producer: publish finished chunk (vmcnt drain + agent release)
    if (role == 0 && (t & (CHUNK - 1)) == (CHUNK - 1)) {
      asm volatile("s_waitcnt vmcnt(0)" ::: "memory");
      __syncthreads();
      if (tid == 0) {
        __builtin_amdgcn_fence(__ATOMIC_RELEASE, "agent");
        __hip_atomic_store(&flag0[t >> CHUNK_LOG], 1u, __ATOMIC_RELEASE,
                           __HIP_MEMORY_SCOPE_AGENT);
      }
    }
  }
}

__device__ __forceinline__ void gemm_worker_run(
    const float* hs0, float* pre, const float* wih1T, const float* bias1,
    unsigned* flag0, unsigned* flag1, int w, char* smem) {
  float* hsl = (float*)smem;   // [32][256] = 32 KB
  int tid = threadIdx.x;
  for (int cnk = 0; cnk < NCHUNK; ++cnk) {
    if (tid == 0) {
      while (__hip_atomic_load(&flag0[cnk], __ATOMIC_ACQUIRE,
                               __HIP_MEMORY_SCOPE_AGENT) == 0u)
        __builtin_amdgcn_s_sleep(8);
    }
    __syncthreads();
    __builtin_amdgcn_fence(__ATOMIC_ACQUIRE, "agent");
    int r0 = cnk * CHUNK + w * 32;
    for (int i = tid; i < 32 * 256; i += 512)
      hsl[i] = hs0[(size_t)(r0 + (i >> 8)) * 256 + (i & 255)];
    __syncthreads();
    for (int half = 0; half < 2; ++half) {
      int p = half * 512 + tid;
      float bv = bias1[p];
      for (int rb = 0; rb < 4; ++rb) {
        float accw[8];
#pragma unroll
        for (int r = 0; r < 8; ++r) accw[r] = bv;
        for (int k = 0; k < 256; ++k) {
          float wv = wih1T[k * 1024 + p];
#pragma unroll
          for (int r = 0; r < 8; ++r)
            accw[r] += hsl[(rb * 8 + r) * 256 + k] * wv;
        }
#pragma unroll
        for (int r = 0; r < 8; ++r)
          pre[(size_t)(r0 + rb * 8 + r) * 1024 + p] = accw[r];
      }
    }
    asm volatile("s_waitcnt vmcnt(0)" ::: "memory");
    __syncthreads();
    if (tid == 0) {
      __builtin_amdgcn_fence(__ATOMIC_RELEASE, "agent");
      __hip_atomic_fetch_add(&flag1[cnk], 1u, __ATOMIC_RELEASE,
                             __HIP_MEMORY_SCOPE_AGENT);
    }
    __syncthreads();
  }
}

__global__ __launch_bounds__(512) void lstm_pipe_kernel(
    float* pre,                       // [T][1024]: L0 input (pre0); workers overwrite with pre1
    const _Float16* wfrag,            // [2][64][8][64][8]
    float* hs0,
    float* h0f, float* c0f, float* h1f, float* c1f,
    const float* wih1T, const float* bias1,
    unsigned* flags) {                // flags[0..127]=flag0, [128..255]=flag1
  extern __shared__ __align__(16) char smem[];
  unsigned* flag0 = flags;
  unsigned* flag1 = flags + NCHUNK;
  int bid = blockIdx.x;
  if (bid == 0) {
    lstm_layer_run(pre, wfrag, hs0, h0f, c0f, 1, 0, flag0, flag1, smem);
  } else if (bid == 1) {
    lstm_layer_run(pre, wfrag + 262144, nullptr, h1f, c1f, 0, 1, flag0, flag1, smem);
  } else {
    gemm_worker_run(hs0, pre, wih1T, bias1, flag0, flag1, bid - 2, smem);
  }
}

// ---------------- gather outputs ----------------
__global__ void finalize_kernel(const float* __restrict__ h0, const float* __restrict__ c0,
                                const float* __restrict__ h1, const float* __restrict__ c1,
                                float* __restrict__ out) {
  int i = blockIdx.x * blockDim.x + threadIdx.x;
  if (i < 256) out[i] = h1[i];
  else if (i < 512) out[i] = h0[i - 256];
  else if (i < 768) out[i] = h1[i - 512];
  else if (i < 1024) out[i] = c0[i - 768];
  else if (i < 1280) out[i] = c1[i - 1024];
}

extern "C" void kernel_launch(void* const* d_in, const int* in_sizes, int n_in,
                              void* d_out, int out_size, void* d_ws, size_t ws_size,
                              hipStream_t stream) {
  const float* fov      = (const float*)d_in[0];
  const float* own_pos  = (const float*)d_in[1];
  const float* opponent = (const float*)d_in[2];
  const float* cost     = (const float*)d_in[3];
  const int*   action   = (const int*)d_in[4];
  const float* conv1_w  = (const float*)d_in[5];
  const float* conv1_b  = (const float*)d_in[6];
  const float* conv2_w  = (const float*)d_in[7];
  const float* conv2_b  = (const float*)d_in[8];
  const float* obs_w    = (const float*)d_in[9];
  const float* obs_b    = (const float*)d_in[10];
  const float* pos_w    = (const float*)d_in[11];
  const float* pos_b    = (const float*)d_in[12];
  const float* opp_w    = (const float*)d_in[13];
  const float* opp_b    = (const float*)d_in[14];
  const float* act_emb  = (const float*)d_in[15];
  const float* wih0     = (const float*)d_in[16];
  const float* whh0     = (const float*)d_in[17];
  const float* bih0     = (const float*)d_in[18];
  const float* bhh0     = (const float*)d_in[19];
  const float* wih1     = (const float*)d_in[20];
  const float* whh1     = (const float*)d_in[21];
  const float* bih1     = (const float*)d_in[22];
  const float* bhh1     = (const float*)d_in[23];

  char* ws = (char*)d_ws;
  size_t off = 0;
  auto alloc = [&](size_t bytes) {
    void* p = ws + off;
    off += (bytes + 255) & ~(size_t)255;
    return p;
  };
  float* feat   = (float*)alloc((size_t)T_LEN * 192 * 4);
  float* pre    = (float*)alloc((size_t)T_LEN * 1024 * 4);
  float* hs0    = (float*)alloc((size_t)T_LEN * 256 * 4);
  float* obs_wT = (float*)alloc(1600 * 128 * 4);
  float* wih0T  = (float*)alloc(192 * 1024 * 4);
  float* wih1T  = (float*)alloc(256 * 1024 * 4);
  _Float16* wfrag = (_Float16*)alloc((size_t)2 * 262144 * 2);
  float* bias0  = (float*)alloc(1024 * 4);
  float* bias1  = (float*)alloc(1024 * 4);
  float* h0f = (float*)alloc(256 * 4);
  float* c0f = (float*)alloc(256 * 4);
  float* h1f = (float*)alloc(256 * 4);
  float* c1f = (float*)alloc(256 * 4);
  unsigned* flags = (unsigned*)alloc(2 * NCHUNK * 4);

  static int lds_attr_set = 0;
  if (!lds_attr_set) {
    hipFuncSetAttribute((const void*)lstm_pipe_kernel,
                        hipFuncAttributeMaxDynamicSharedMemorySize, SMEM_BYTES);
    lds_attr_set = 1;
  }

  prep_kernel<<<2048, 256, 0, stream>>>(obs_w, wih0, wih1, whh0, whh1,
                                        bih0, bhh0, bih1, bhh1,
                                        obs_wT, wih0T, wih1T, wfrag, bias0, bias1);
  encoder_kernel<<<T_LEN / ETS, 256, 0, stream>>>(fov, own_pos, opponent, cost, action,
      conv1_w, conv1_b, conv2_w, conv2_b, obs_wT, obs_b, pos_w, pos_b, opp_w, opp_b,
      act_emb, feat);
  gemm_bias_kernel<<<4096, 256, 0, stream>>>(feat, wih0T, bias0, pre, T_LEN, 1024, 192);
  hipMemsetAsync(flags, 0, 2 * NCHUNK * 4, stream);
  lstm_pipe_kernel<<<2 + NW, 512, SMEM_BYTES, stream>>>(
      pre, wfrag, hs0, h0f, c0f, h1f, c1f, wih1T, bias1, flags);
  finalize_kernel<<<5, 256, 0, stream>>>(h0f, c0f, h1f, c1f, (float*)d_out);
}